// Round 9
// baseline (190.839 us; speedup 1.0000x reference)
//
#include <hip/hip_runtime.h>
#include <hip/hip_bf16.h>
#include <math.h>

#define N_ROWS 8192
#define DIM 256
#define NCLS 128
// scale folded into normalized rows: sqrt((1/0.07) * log2(e))
#define ROW_SCALE 4.539816f
#define CLAMP_Y 14.426950408889634f   // 10 * log2(e)
#define NEG2C (-28.853900817779268f)  // -2 * CLAMP_Y
#define LN2F 0.6931471805599453f

typedef short bf16x8 __attribute__((ext_vector_type(8)));
typedef float f32x4 __attribute__((ext_vector_type(4)));

#define AS1 __attribute__((address_space(1)))
#define AS3 __attribute__((address_space(3)))

__device__ __forceinline__ void load16_to_lds(const void* g, void* lds) {
  // LDS dest = wave-uniform base (+ lane*16 added by HW); gptr is per-lane
  __builtin_amdgcn_global_load_lds((const AS1 void*)g, (AS3 void*)lds, 16, 0, 0);
}

__device__ __forceinline__ unsigned short f2bf(float x) {
  union { __hip_bfloat16 b; unsigned short u; } cv;
  cv.b = __float2bfloat16(x);
  return cv.u;
}

__device__ __forceinline__ float fast_exp2(float x) {
#if __has_builtin(__builtin_amdgcn_exp2f)
  return __builtin_amdgcn_exp2f(x);
#else
  return exp2f(x);
#endif
}

// clamp(x, -2C, 0) in one v_med3_f32
__device__ __forceinline__ float clamp_neg(float x) {
#if __has_builtin(__builtin_amdgcn_fmed3f)
  return __builtin_amdgcn_fmed3f(x, NEG2C, 0.0f);
#else
  return fminf(0.0f, fmaxf(NEG2C, x));
#endif
}

// ---------------- row-normalize*ROW_SCALE -> bf16, zero S/P -----------------
__global__ __launch_bounds__(256) void normalize_kernel(const float* __restrict__ f,
                                                        unsigned short* __restrict__ fnb,
                                                        float* __restrict__ S,
                                                        float* __restrict__ P) {
  const int row = blockIdx.x * 4 + (threadIdx.x >> 6);
  const int l = threadIdx.x & 63;
  const float4 v = ((const float4*)(f + (size_t)row * DIM))[l];
  float ss = v.x * v.x + v.y * v.y + v.z * v.z + v.w * v.w;
#pragma unroll
  for (int m = 32; m >= 1; m >>= 1) ss += __shfl_xor(ss, m, 64);
  const float inv = ROW_SCALE / fmaxf(sqrtf(ss), 1e-6f);
  ushort4 o;
  o.x = f2bf(v.x * inv);
  o.y = f2bf(v.y * inv);
  o.z = f2bf(v.z * inv);
  o.w = f2bf(v.w * inv);
  ((ushort4*)(fnb + (size_t)row * DIM))[l] = o;
  if (l == 0) { S[row] = 0.f; P[row] = 0.f; }
}

// stage one 8KB B-chunk (128 j-rows x K=32 slice KS) into ring buffer BUF
#define STAGE_B(JB, KS, BUF)                                                    \
  {                                                                             \
    _Pragma("unroll") for (int r_ = 0; r_ < 2; ++r_) {                          \
      const int off_ = r_ * 1024 + l * 16;                                      \
      const int row_ = w * 32 + (off_ >> 6);                                    \
      const int c_ = ((off_ >> 4) & 3) ^ ((row_ >> 1) & 3);                     \
      load16_to_lds(fnb_c + (size_t)((JB) + row_) * 512 + (KS) * 64 + c_ * 16,  \
                    (char*)Bsh + (BUF) * 8192 + w * 2048 + r_ * 1024);          \
    }                                                                           \
  }

// ---------------- triangular-strip GEMM + exp/positive reductions -----------
// 1056 blocks x 256 threads: block = (bi, chunk of up to 2 j-tiles 128 wide).
// PIPELINE-DEPTH STRUCTURE (resubmit of round 8; container infra failed):
// each wave owns 32 I-rows with ALL its A-fragments in REGISTERS
// (af[2mi][8kt], 64 VGPR), loaded once per block via a 32KB LDS bounce (two
// K-halves). B streams through a 4-buffer LDS ring (4 x 8KB): phase kt reads
// buf[kt&3]; the stage for kt+3 issues AFTER barrier(kt) (its target was
// last read at kt-1 -> WAR-safe with ONE barrier per phase); steady-state
// s_waitcnt vmcnt(4) keeps 2 stages (3 phases, ~450cy) in flight across
// barriers -- NO vmcnt(0) in the loop (m218/T4). Tile transitions stage the
// next tile's B0-2 in the kt=5..7 slots (ring parity continuous); last tile
// tails 4/2/0. Labels hoisted to prologue so only epilogue atomics (newest
// in FIFO) share the vmcnt; they drain incidentally under the counted waits.
// Col sums cross-wave via redbuf (aliases dead A-bounce); rows flushed once
// per block (each row owned by exactly one wave). Accumulator biased by
// -CLAMP_Y: epilogue = v_med3 + exp2; diagonal gives e=1/pv=0 (finalize fixes).
__global__ __launch_bounds__(256, 2) void simloss_tri(
    const unsigned short* __restrict__ fnb, const int* __restrict__ labels,
    float* __restrict__ S, float* __restrict__ P) {
  __shared__ __align__(16) unsigned short Bsh[4][128 * 32];    // 32 KB ring
  __shared__ __align__(16) unsigned short Abounce[128 * 128];  // 32 KB bounce
  float(*redbuf)[128][2] = (float(*)[128][2])(void*)Abounce;   // alias, 4 KB

  const int tid = threadIdx.x;
  const int w = tid >> 6;   // wave 0..3 -> owns rows w*32..w*32+31
  const int l = tid & 63;
  const int ln15 = l & 15;
  const int q = l >> 4;

  // decode blockIdx.x -> (bi, chunk); row bi has ceil((64-bi)/2) chunks
  int b = blockIdx.x, bi;
  for (bi = 0; bi < 64; ++bi) {
    const int nch = (64 - bi + 1) >> 1;
    if (b < nch) break;
    b -= nch;
  }
  const int ibase = bi * 128;
  const int j0 = bi + b * 2;
  const int jn = (64 - j0 < 2) ? (64 - j0) : 2;
  const char* fnb_c = (const char*)fnb;

  // ---- prologue: stage A half-1 (k 0..127) into bounce; load all labels
#pragma unroll
  for (int r = 0; r < 8; ++r) {
    const int off = r * 4096 + w * 1024 + l * 16;
    const int row = off >> 8;                      // 256 B per bounce row
    const int c = ((off >> 4) & 15) ^ (row & 7);
    load16_to_lds(fnb_c + (size_t)(ibase + row) * 512 + c * 16,
                  (char*)Abounce + r * 4096 + w * 1024);
  }
  int rowlab[2][4];
#pragma unroll
  for (int mi = 0; mi < 2; ++mi)
#pragma unroll
    for (int rg = 0; rg < 4; ++rg)
      rowlab[mi][rg] = labels[ibase + w * 32 + mi * 16 + q * 4 + rg];
  int labJ0[8], labJ1[8];
  {
    const int j1 = (jn > 1) ? (j0 + 1) : j0;
#pragma unroll
    for (int ni = 0; ni < 8; ++ni) {
      labJ0[ni] = labels[j0 * 128 + ni * 16 + ln15];
      labJ1[ni] = labels[j1 * 128 + ni * 16 + ln15];
    }
  }
  asm volatile("s_waitcnt vmcnt(0)" ::: "memory");
  __builtin_amdgcn_s_barrier();
  asm volatile("" ::: "memory");

  // ---- read af for kt 0..3 from bounce
  bf16x8 af[2][8];
#pragma unroll
  for (int kt2 = 0; kt2 < 4; ++kt2)
#pragma unroll
    for (int mi = 0; mi < 2; ++mi) {
      const int row = w * 32 + mi * 16 + ln15;
      const int c = (kt2 * 4 + q) ^ (row & 7);
      af[mi][kt2] = *(const bf16x8*)((const char*)Abounce + row * 256 + c * 16);
    }
  asm volatile("s_waitcnt lgkmcnt(0)" ::: "memory");
  __builtin_amdgcn_s_barrier();
  asm volatile("" ::: "memory");

  // ---- stage A half-2 (k 128..255) + first tile's B0,B1,B2
#pragma unroll
  for (int r = 0; r < 8; ++r) {
    const int off = r * 4096 + w * 1024 + l * 16;
    const int row = off >> 8;
    const int c = ((off >> 4) & 15) ^ (row & 7);
    load16_to_lds(fnb_c + (size_t)(ibase + row) * 512 + 256 + c * 16,
                  (char*)Abounce + r * 4096 + w * 1024);
  }
  STAGE_B(j0 * 128, 0, 0);
  STAGE_B(j0 * 128, 1, 1);
  STAGE_B(j0 * 128, 2, 2);
  asm volatile("s_waitcnt vmcnt(6)" ::: "memory");  // A half-2 done; B0-2 fly
  __builtin_amdgcn_s_barrier();
  asm volatile("" ::: "memory");
#pragma unroll
  for (int kt2 = 0; kt2 < 4; ++kt2)
#pragma unroll
    for (int mi = 0; mi < 2; ++mi) {
      const int row = w * 32 + mi * 16 + ln15;
      const int c = (kt2 * 4 + q) ^ (row & 7);
      af[mi][4 + kt2] = *(const bf16x8*)((const char*)Abounce + row * 256 + c * 16);
    }
  // (af half-2 reads drained by the first phase's lgkmcnt(0))

  float rs[2][4], rp[2][4];
#pragma unroll
  for (int mi = 0; mi < 2; ++mi)
#pragma unroll
    for (int rg = 0; rg < 4; ++rg) { rs[mi][rg] = 0.f; rp[mi][rg] = 0.f; }

  for (int jt = 0; jt < jn; ++jt) {
    const int jbase = (j0 + jt) * 128;
    const bool lastt = (jt + 1 == jn);
    int labJ[8];
#pragma unroll
    for (int ni = 0; ni < 8; ++ni) labJ[ni] = (jt == 0) ? labJ0[ni] : labJ1[ni];

    f32x4 acc[2][8];
#pragma unroll
    for (int mi = 0; mi < 2; ++mi)
#pragma unroll
      for (int ni = 0; ni < 8; ++ni) acc[mi][ni] = (f32x4)(-CLAMP_Y);

    // ---- 4-deep ring K loop: ONE barrier/phase, counted vmcnt ----
#pragma unroll
    for (int kt = 0; kt < 8; ++kt) {
      // stage(kt) guaranteed landed; 2 newer stages stay in flight
      if (lastt && kt == 6)      asm volatile("s_waitcnt vmcnt(2)" ::: "memory");
      else if (lastt && kt == 7) asm volatile("s_waitcnt vmcnt(0)" ::: "memory");
      else                       asm volatile("s_waitcnt vmcnt(4)" ::: "memory");
      asm volatile("s_waitcnt lgkmcnt(0)" ::: "memory");  // prev-phase reads
      __builtin_amdgcn_s_barrier();
      asm volatile("" ::: "memory");
      __builtin_amdgcn_sched_barrier(0);
      // stage for kt+3 (target buf last read at kt-1; all waves past bar(kt))
      if (kt < 5) {
        STAGE_B(jbase, kt + 3, (kt + 3) & 3);
      } else if (!lastt) {
        STAGE_B(jbase + 128, kt - 5, (kt - 5) & 3);  // next tile's B0..B2
      }
      const char* bb = (const char*)Bsh + (kt & 3) * 8192;
      bf16x8 bfr[8];
#pragma unroll
      for (int ni = 0; ni < 8; ++ni) {
        const int n = ni * 16 + ln15;
        const int c = q ^ ((n >> 1) & 3);
        bfr[ni] = *(const bf16x8*)(bb + n * 64 + c * 16);
      }
      __builtin_amdgcn_s_setprio(1);
#pragma unroll
      for (int mi = 0; mi < 2; ++mi)
#pragma unroll
        for (int ni = 0; ni < 8; ++ni)
          acc[mi][ni] = __builtin_amdgcn_mfma_f32_16x16x32_bf16(
              af[mi][kt], bfr[ni], acc[mi][ni], 0, 0, 0);
      __builtin_amdgcn_s_setprio(0);
      __builtin_amdgcn_sched_barrier(0);
      asm volatile("" ::: "memory");
    }

    // ---- epilogue: exp-sum + positive-sim accumulate (rows + cols) ----
    float cs[8], cp[8];
#pragma unroll
    for (int ni = 0; ni < 8; ++ni) { cs[ni] = 0.f; cp[ni] = 0.f; }
#pragma unroll
    for (int mi = 0; mi < 2; ++mi)
#pragma unroll
      for (int ni = 0; ni < 8; ++ni)
#pragma unroll
        for (int rg = 0; rg < 4; ++rg) {
          const float yc = clamp_neg(acc[mi][ni][rg]);  // clamp(sim)*log2e - C
          const float e = fast_exp2(yc);
          const float pv = (labJ[ni] == rowlab[mi][rg]) ? yc : 0.0f;
          rs[mi][rg] += e;
          rp[mi][rg] += pv;
          cs[ni] += e;
          cp[ni] += pv;
        }
    // reduce col partials over q (rows) within the wave
#pragma unroll
    for (int m = 16; m <= 32; m <<= 1)
#pragma unroll
      for (int ni = 0; ni < 8; ++ni) {
        cs[ni] += __shfl_xor(cs[ni], m, 64);
        cp[ni] += __shfl_xor(cp[ni], m, 64);
      }
    if (q == 0) {
#pragma unroll
      for (int ni = 0; ni < 8; ++ni) {
        redbuf[w][ni * 16 + ln15][0] = cs[ni];
        redbuf[w][ni * 16 + ln15][1] = cp[ni];
      }
    }
    asm volatile("s_waitcnt lgkmcnt(0)" ::: "memory");
    __builtin_amdgcn_s_barrier();
    asm volatile("" ::: "memory");
    // combine 4 wave-slices and flush cols -> rows of bj (skip diagonal)
    if ((j0 + jt) != bi) {
      const int col = w * 32 + (l & 31);
      const int arr = l >> 5;
      const float v = redbuf[0][col][arr] + redbuf[1][col][arr] +
                      redbuf[2][col][arr] + redbuf[3][col][arr];
      float* dst = arr ? P : S;
      atomicAdd(&dst[jbase + col], v);
    }
    // redbuf next written at next tile's epilogue (>=8 barriers away)
  }

  // ---- row-sum flush: reduce over ln15 (cols); each row owned by one wave
#pragma unroll
  for (int m = 1; m <= 8; m <<= 1)
#pragma unroll
    for (int mi = 0; mi < 2; ++mi)
#pragma unroll
      for (int rg = 0; rg < 4; ++rg) {
        rs[mi][rg] += __shfl_xor(rs[mi][rg], m, 64);
        rp[mi][rg] += __shfl_xor(rp[mi][rg], m, 64);
      }
  if (ln15 == 0) {
#pragma unroll
    for (int mi = 0; mi < 2; ++mi)
#pragma unroll
      for (int rg = 0; rg < 4; ++rg) {
        const int rl = ibase + w * 32 + mi * 16 + q * 4 + rg;
        atomicAdd(&S[rl], rs[mi][rg]);
        atomicAdd(&P[rl], rp[mi][rg]);
      }
  }
}

// ---------------- finalize: label hist (LDS) + per-row loss + mean ----------
// With biased accumulator: S = sum_j exp(sim_c - 10) incl diag(=1);
// P = sum_{pos} (sim_c*log2e - C) with diag contributing 0  =>
// loss_i = log(S-1) - ln2 * P / cnt      (the +10/-10 cancel exactly)
__global__ __launch_bounds__(1024) void finalize_kernel(
    const float* __restrict__ S, const float* __restrict__ P,
    const int* __restrict__ labels, float* __restrict__ out) {
  __shared__ int h[NCLS];
  if (threadIdx.x < NCLS) h[threadIdx.x] = 0;
  __syncthreads();
  for (int i = threadIdx.x; i < N_ROWS; i += 1024) atomicAdd(&h[labels[i]], 1);
  __syncthreads();

  float lsum = 0.f, vsum = 0.f;
  for (int i = threadIdx.x; i < N_ROWS; i += 1024) {
    const int cnt = h[labels[i]] - 1;  // positives excluding self
    if (cnt > 0) {
      lsum += logf(S[i] - 1.0f) - LN2F * P[i] / (float)cnt;
      vsum += 1.0f;
    }
  }
#pragma unroll
  for (int m = 32; m >= 1; m >>= 1) {
    lsum += __shfl_xor(lsum, m, 64);
    vsum += __shfl_xor(vsum, m, 64);
  }
  __shared__ float ls[16], vs[16];
  const int wv = threadIdx.x >> 6;
  if ((threadIdx.x & 63) == 0) { ls[wv] = lsum; vs[wv] = vsum; }
  __syncthreads();
  if (threadIdx.x == 0) {
    float L = 0.f, V = 0.f;
    for (int k = 0; k < 16; ++k) { L += ls[k]; V += vs[k]; }
    out[0] = (V > 0.f) ? (L / fmaxf(V, 1.0f)) : 0.f;
  }
}

extern "C" void kernel_launch(void* const* d_in, const int* in_sizes, int n_in,
                              void* d_out, int out_size, void* d_ws, size_t ws_size,
                              hipStream_t stream) {
  const float* feat = (const float*)d_in[0];
  const int* labels = (const int*)d_in[1];
  float* out = (float*)d_out;

  char* ws = (char*)d_ws;
  unsigned short* fnb = (unsigned short*)ws;            // bf16 [8192][256], 4 MB
  float* S = (float*)(ws + (size_t)N_ROWS * DIM * 2);   // [8192]
  float* P = S + N_ROWS;                                // [8192]

  normalize_kernel<<<N_ROWS / 4, 256, 0, stream>>>(feat, fnb, S, P);
  simloss_tri<<<1056, 256, 0, stream>>>(fnb, labels, S, P);
  finalize_kernel<<<1, 1024, 0, stream>>>(S, P, labels, out);
}

// Round 10
// 144.462 us; speedup vs baseline: 1.3210x; 1.3210x over previous
//
#include <hip/hip_runtime.h>
#include <hip/hip_bf16.h>
#include <math.h>

#define N_ROWS 8192
#define DIM 256
#define NCLS 128
// scale folded into normalized rows: sqrt((1/0.07) * log2(e))
#define ROW_SCALE 4.539816f
#define CLAMP_Y 14.426950408889634f   // 10 * log2(e)
#define NEG2C (-28.853900817779268f)  // -2 * CLAMP_Y
#define LN2F 0.6931471805599453f

typedef short bf16x8 __attribute__((ext_vector_type(8)));
typedef float f32x4 __attribute__((ext_vector_type(4)));

#define AS1 __attribute__((address_space(1)))
#define AS3 __attribute__((address_space(3)))

__device__ __forceinline__ void load16_to_lds(const void* g, void* lds) {
  // LDS dest = wave-uniform base (+ lane*16 added by HW); gptr is per-lane
  __builtin_amdgcn_global_load_lds((const AS1 void*)g, (AS3 void*)lds, 16, 0, 0);
}

__device__ __forceinline__ unsigned short f2bf(float x) {
  union { __hip_bfloat16 b; unsigned short u; } cv;
  cv.b = __float2bfloat16(x);
  return cv.u;
}

__device__ __forceinline__ float fast_exp2(float x) {
#if __has_builtin(__builtin_amdgcn_exp2f)
  return __builtin_amdgcn_exp2f(x);
#else
  return exp2f(x);
#endif
}

// clamp(x, -2C, 0) in one v_med3_f32
__device__ __forceinline__ float clamp_neg(float x) {
#if __has_builtin(__builtin_amdgcn_fmed3f)
  return __builtin_amdgcn_fmed3f(x, NEG2C, 0.0f);
#else
  return fminf(0.0f, fmaxf(NEG2C, x));
#endif
}

// ---------------- row-normalize*ROW_SCALE -> bf16, zero S/P -----------------
__global__ __launch_bounds__(256) void normalize_kernel(const float* __restrict__ f,
                                                        unsigned short* __restrict__ fnb,
                                                        float* __restrict__ S,
                                                        float* __restrict__ P) {
  const int row = blockIdx.x * 4 + (threadIdx.x >> 6);
  const int l = threadIdx.x & 63;
  const float4 v = ((const float4*)(f + (size_t)row * DIM))[l];
  float ss = v.x * v.x + v.y * v.y + v.z * v.z + v.w * v.w;
#pragma unroll
  for (int m = 32; m >= 1; m >>= 1) ss += __shfl_xor(ss, m, 64);
  const float inv = ROW_SCALE / fmaxf(sqrtf(ss), 1e-6f);
  ushort4 o;
  o.x = f2bf(v.x * inv);
  o.y = f2bf(v.y * inv);
  o.z = f2bf(v.z * inv);
  o.w = f2bf(v.w * inv);
  ((ushort4*)(fnb + (size_t)row * DIM))[l] = o;
  if (l == 0) { S[row] = 0.f; P[row] = 0.f; }
}

// ---------------- triangular-strip GEMM + exp/positive reductions -----------
// 1056 blocks x 256 threads: block = (bi, chunk of up to 2 j-tiles 128 wide).
// BARRIER-FREE K-LOOP: A (128x256, 64 KB) resident in LDS (read-only after
// one sync -> no loop barriers). B fragments are read DIRECT from global
// (L2-resident; addressing proven correct in R1) into a depth-3 register
// ring bpp[3][4] (48 VGPR): the load for global phase g+3 issues right after
// the MFMAs of phase g consume the same slot -> prefetch lead ~2 full phases
// (300-500 cy) > L2-hit latency (~200 cy), fixing R1's depth-1 flaw. Plain-C
// loads: the compiler emits its own counted vmcnt before each dependent MFMA
// (no vmcnt(0) drains; its proven strength). Statically unrolled 16-phase
// schedule spans both j-tiles: tile-2's k0..k2 prefetch during tile-1's
// phases 5-7 and fly through the epilogue. 5 barriers/block total.
// ARCH-VGPR BUDGET <=128 (R2/R5/R6/R9 spill rule): labels + rs/rp moved to
// per-tile transient epilogue; sustained = bpp 48 + addressing (~25).
// Accumulator biased by -CLAMP_Y: epilogue = v_med3 + exp2; diagonal gives
// e=1 / pv=0 exactly (fixed in finalize). Col sums -> rows of bj via
// symmetry (skip diagonal tile); rows flushed per tile (both wc waves
// atomic directly).
__global__ __launch_bounds__(256, 2) void simloss_tri(
    const unsigned short* __restrict__ fnb, const int* __restrict__ labels,
    float* __restrict__ S, float* __restrict__ P) {
  __shared__ __align__(16) unsigned short Atile[128 * 256];  // 64 KB
  __shared__ float colbuf[128][2];                           // 1 KB

  const int tid = threadIdx.x;
  const int w = tid >> 6;   // wave 0..3
  const int l = tid & 63;
  const int wr = w >> 1;    // wave row -> 64 rows
  const int wc = w & 1;     // wave col -> 64 cols
  const int ln15 = l & 15;
  const int q = l >> 4;

  // decode blockIdx.x -> (bi, chunk); row bi has ceil((64-bi)/2) chunks
  int b = blockIdx.x, bi;
  for (bi = 0; bi < 64; ++bi) {
    const int nch = (64 - bi + 1) >> 1;
    if (b < nch) break;
    b -= nch;
  }
  const int ibase = bi * 128;
  const int j0 = bi + b * 2;
  const int jn = (64 - j0 < 2) ? (64 - j0) : 2;
  const int j1 = (jn > 1) ? (j0 + 1) : j0;   // clamped (prefetch target safe)
  const char* fnb_c = (const char*)fnb;

  // ---- stage A [128][256] bf16; 16B chunk c of row r stored at c^(r&7)
#pragma unroll
  for (int r = 0; r < 16; ++r) {
    const int off = r * 4096 + w * 1024 + l * 16;
    const int row = off >> 9;                    // 512 B per row
    const int c = ((off >> 4) & 31) ^ (row & 7);
    load16_to_lds(fnb_c + (size_t)(ibase + row) * 512 + c * 16,
                  (char*)Atile + r * 4096 + w * 1024);
  }

  // ---- per-lane B base (R1-proven): row (wc*64+ln15), byte q*16 in k-slice
  const char* bptr = fnb_c + (size_t)(wc * 64 + ln15) * 512 + q * 16;

  // ---- prime the depth-3 ring with tile-1 slices k0,k1,k2
  bf16x8 bpp[3][4];
#pragma unroll
  for (int s = 0; s < 3; ++s)
#pragma unroll
    for (int ni = 0; ni < 4; ++ni)
      bpp[s][ni] =
          *(const bf16x8*)(bptr + (size_t)(j0 * 128 + ni * 16) * 512 + s * 64);

  __syncthreads();  // A staged (drains vmcnt; bpp data also landed)

  f32x4 acc[4][4];
#pragma unroll
  for (int mi = 0; mi < 4; ++mi)
#pragma unroll
    for (int ni = 0; ni < 4; ++ni) acc[mi][ni] = (f32x4)(-CLAMP_Y);

// one phase of the global 16-phase schedule (G literal 0..15):
// consume bpp[G%3] for tile (G<8 ? j0 : j1), then refill the SAME slot with
// global phase G+3 (compiler orders refill after the consuming MFMAs).
#define PHASE(G)                                                               \
  {                                                                            \
    const int kt_ = (G) & 7;                                                   \
    bf16x8 af_[4];                                                             \
    _Pragma("unroll") for (int mi = 0; mi < 4; ++mi) {                         \
      const int row_ = wr * 64 + mi * 16 + ln15;                               \
      const int c_ = (kt_ * 4 + q) ^ (row_ & 7);                               \
      af_[mi] = *(const bf16x8*)((const char*)Atile + row_ * 512 + c_ * 16);   \
    }                                                                          \
    _Pragma("unroll") for (int mi = 0; mi < 4; ++mi)                           \
        _Pragma("unroll") for (int ni = 0; ni < 4; ++ni) acc[mi][ni] =         \
        __builtin_amdgcn_mfma_f32_16x16x32_bf16(af_[mi], bpp[(G) % 3][ni],     \
                                                acc[mi][ni], 0, 0, 0);         \
    if ((G) + 3 <= 15) {                                                       \
      const int jb2_ = (((G) + 3) >= 8) ? j1 : j0;                             \
      const int kt2_ = ((G) + 3) & 7;                                          \
      _Pragma("unroll") for (int ni = 0; ni < 4; ++ni) bpp[((G) + 3) % 3][ni] = \
          *(const bf16x8*)(bptr + (size_t)(jb2_ * 128 + ni * 16) * 512 +       \
                           kt2_ * 64);                                         \
    }                                                                          \
  }

// per-tile epilogue: transient labels + rs/rp/cs/cp, col-sym flush, row flush
#define EPILOGUE(JBT)                                                          \
  {                                                                            \
    const int jbase_ = (JBT) * 128;                                            \
    int labJ_[4], rowlab_[16];                                                 \
    _Pragma("unroll") for (int ni = 0; ni < 4; ++ni) labJ_[ni] =               \
        labels[jbase_ + wc * 64 + ni * 16 + ln15];                             \
    _Pragma("unroll") for (int mi = 0; mi < 4; ++mi)                           \
        _Pragma("unroll") for (int rg = 0; rg < 4; ++rg) rowlab_[mi * 4 + rg] = \
        labels[ibase + wr * 64 + mi * 16 + q * 4 + rg];                        \
    float rs_[16], rp_[16], cs_[4], cp_[4];                                    \
    _Pragma("unroll") for (int t = 0; t < 16; ++t) { rs_[t] = 0.f; rp_[t] = 0.f; } \
    _Pragma("unroll") for (int t = 0; t < 4; ++t) { cs_[t] = 0.f; cp_[t] = 0.f; } \
    _Pragma("unroll") for (int mi = 0; mi < 4; ++mi)                           \
        _Pragma("unroll") for (int ni = 0; ni < 4; ++ni)                       \
        _Pragma("unroll") for (int rg = 0; rg < 4; ++rg) {                     \
      const float yc_ = clamp_neg(acc[mi][ni][rg]);                            \
      const float e_ = fast_exp2(yc_);                                         \
      const float pv_ = (labJ_[ni] == rowlab_[mi * 4 + rg]) ? yc_ : 0.0f;      \
      rs_[mi * 4 + rg] += e_;                                                  \
      rp_[mi * 4 + rg] += pv_;                                                 \
      cs_[ni] += e_;                                                           \
      cp_[ni] += pv_;                                                          \
    }                                                                          \
    _Pragma("unroll") for (int m = 16; m <= 32; m <<= 1)                       \
        _Pragma("unroll") for (int t = 0; t < 4; ++t) {                        \
      cs_[t] += __shfl_xor(cs_[t], m, 64);                                     \
      cp_[t] += __shfl_xor(cp_[t], m, 64);                                     \
    }                                                                          \
    __syncthreads(); /* prior colbuf reads done (tile 2); tile-2 prefetch data lands */ \
    if (wr == 1 && q == 0) {                                                   \
      _Pragma("unroll") for (int ni = 0; ni < 4; ++ni) {                       \
        const int cl_ = wc * 64 + ni * 16 + ln15;                              \
        colbuf[cl_][0] = cs_[ni];                                              \
        colbuf[cl_][1] = cp_[ni];                                              \
      }                                                                        \
    }                                                                          \
    __syncthreads();                                                           \
    if (wr == 0 && q == 0 && (JBT) != bi) {                                    \
      _Pragma("unroll") for (int ni = 0; ni < 4; ++ni) {                       \
        const int cl_ = wc * 64 + ni * 16 + ln15;                              \
        atomicAdd(&S[jbase_ + cl_], cs_[ni] + colbuf[cl_][0]);                 \
        atomicAdd(&P[jbase_ + cl_], cp_[ni] + colbuf[cl_][1]);                 \
      }                                                                        \
    }                                                                          \
    _Pragma("unroll") for (int m = 1; m <= 8; m <<= 1)                         \
        _Pragma("unroll") for (int t = 0; t < 16; ++t) {                       \
      rs_[t] += __shfl_xor(rs_[t], m, 64);                                     \
      rp_[t] += __shfl_xor(rp_[t], m, 64);                                     \
    }                                                                          \
    if (ln15 == 0) { /* both wc waves flush directly (2 atomics/row/tile) */   \
      _Pragma("unroll") for (int t = 0; t < 16; ++t) {                         \
        const int rl_ = ibase + wr * 64 + (t >> 2) * 16 + q * 4 + (t & 3);     \
        atomicAdd(&S[rl_], rs_[t]);                                            \
        atomicAdd(&P[rl_], rp_[t]);                                            \
      }                                                                        \
    }                                                                          \
  }

  // ---- tile 1: phases 0..7 (prefetches for 3..10 issue inside) ----
  PHASE(0) PHASE(1) PHASE(2) PHASE(3)
  PHASE(4) PHASE(5) PHASE(6) PHASE(7)
  EPILOGUE(j0)

  if (jn == 2) {
#pragma unroll
    for (int mi = 0; mi < 4; ++mi)
#pragma unroll
      for (int ni = 0; ni < 4; ++ni) acc[mi][ni] = (f32x4)(-CLAMP_Y);
    // ---- tile 2: phases 8..15 (k0..k2 already in the ring) ----
    PHASE(8) PHASE(9) PHASE(10) PHASE(11)
    PHASE(12) PHASE(13) PHASE(14) PHASE(15)
    EPILOGUE(j1)
  }
}

// ---------------- finalize: label hist (LDS) + per-row loss + mean ----------
// With biased accumulator: S = sum_j exp(sim_c - 10) incl diag(=1);
// P = sum_{pos} (sim_c*log2e - C) with diag contributing 0  =>
// loss_i = log(S-1) - ln2 * P / cnt      (the +10/-10 cancel exactly)
__global__ __launch_bounds__(1024) void finalize_kernel(
    const float* __restrict__ S, const float* __restrict__ P,
    const int* __restrict__ labels, float* __restrict__ out) {
  __shared__ int h[NCLS];
  if (threadIdx.x < NCLS) h[threadIdx.x] = 0;
  __syncthreads();
  for (int i = threadIdx.x; i < N_ROWS; i += 1024) atomicAdd(&h[labels[i]], 1);
  __syncthreads();

  float lsum = 0.f, vsum = 0.f;
  for (int i = threadIdx.x; i < N_ROWS; i += 1024) {
    const int cnt = h[labels[i]] - 1;  // positives excluding self
    if (cnt > 0) {
      lsum += logf(S[i] - 1.0f) - LN2F * P[i] / (float)cnt;
      vsum += 1.0f;
    }
  }
#pragma unroll
  for (int m = 32; m >= 1; m >>= 1) {
    lsum += __shfl_xor(lsum, m, 64);
    vsum += __shfl_xor(vsum, m, 64);
  }
  __shared__ float ls[16], vs[16];
  const int wv = threadIdx.x >> 6;
  if ((threadIdx.x & 63) == 0) { ls[wv] = lsum; vs[wv] = vsum; }
  __syncthreads();
  if (threadIdx.x == 0) {
    float L = 0.f, V = 0.f;
    for (int k = 0; k < 16; ++k) { L += ls[k]; V += vs[k]; }
    out[0] = (V > 0.f) ? (L / fmaxf(V, 1.0f)) : 0.f;
  }
}

extern "C" void kernel_launch(void* const* d_in, const int* in_sizes, int n_in,
                              void* d_out, int out_size, void* d_ws, size_t ws_size,
                              hipStream_t stream) {
  const float* feat = (const float*)d_in[0];
  const int* labels = (const int*)d_in[1];
  float* out = (float*)d_out;

  char* ws = (char*)d_ws;
  unsigned short* fnb = (unsigned short*)ws;            // bf16 [8192][256], 4 MB
  float* S = (float*)(ws + (size_t)N_ROWS * DIM * 2);   // [8192]
  float* P = S + N_ROWS;                                // [8192]

  normalize_kernel<<<N_ROWS / 4, 256, 0, stream>>>(feat, fnb, S, P);
  simloss_tri<<<1056, 256, 0, stream>>>(fnb, labels, S, P);
  finalize_kernel<<<1, 1024, 0, stream>>>(S, P, labels, out);
}